// Round 9
// baseline (614.027 us; speedup 1.0000x reference)
//
#include <hip/hip_runtime.h>

#define DIM 64

typedef __attribute__((ext_vector_type(8))) _Float16 half8;
typedef __attribute__((ext_vector_type(4))) _Float16 half4;
typedef __attribute__((ext_vector_type(4))) float floatx4;

// ---------------------------------------------------------------------------
// deg[col[e]] += 1  (int atomics, one-time CSC build)
// ---------------------------------------------------------------------------
__global__ void count_deg_kernel(const int* __restrict__ col,
                                 int* __restrict__ deg, int E) {
    int e = blockIdx.x * blockDim.x + threadIdx.x;
    if (e < E) atomicAdd(&deg[col[e]], 1);
}

// dinv[i] = rsqrt(deg+1), rdinv[i] = sqrt(deg+1)
__global__ void dinv_kernel(const int* __restrict__ deg,
                            float* __restrict__ dinv,
                            float* __restrict__ rdinv, int N) {
    int i = blockIdx.x * blockDim.x + threadIdx.x;
    if (i < N) {
        float d = (float)deg[i] + 1.0f;
        dinv[i] = rsqrtf(d);
        rdinv[i] = sqrtf(d);
    }
}

// --------------------------- exclusive scan over PADDED degree -------------
// pdeg = (deg+7)&~7 so every CSC bucket is a multiple of 8 edges.
__global__ void reduce_chunks_kernel(const int* __restrict__ deg,
                                     int* __restrict__ bs, int N) {
    __shared__ int s[256];
    int t = threadIdx.x;
    int i = blockIdx.x * 256 + t;
    s[t] = (i < N) ? ((deg[i] + 7) & ~7) : 0;
    __syncthreads();
    for (int d = 128; d > 0; d >>= 1) {
        if (t < d) s[t] += s[t + d];
        __syncthreads();
    }
    if (t == 0) bs[blockIdx.x] = s[0];
}

__global__ void scan_block_sums_kernel(int* __restrict__ bs, int nb) {
    __shared__ int s[1024];
    int t = threadIdx.x;
    s[t] = (t < nb) ? bs[t] : 0;
    __syncthreads();
    for (int d = 1; d < 1024; d <<= 1) {
        int v = (t >= d) ? s[t - d] : 0;
        __syncthreads();
        s[t] += v;
        __syncthreads();
    }
    if (t < nb) bs[t] = (t == 0) ? 0 : s[t - 1];
}

__global__ void scan_chunks_kernel(const int* __restrict__ deg,
                                   const int* __restrict__ bs,
                                   int* __restrict__ ptr, int N) {
    __shared__ int s[256];
    int b = blockIdx.x, t = threadIdx.x;
    int i = b * 256 + t;
    int v = (i < N) ? ((deg[i] + 7) & ~7) : 0;
    s[t] = v;
    __syncthreads();
    for (int d = 1; d < 256; d <<= 1) {
        int u = (t >= d) ? s[t - d] : 0;
        __syncthreads();
        s[t] += u;
        __syncthreads();
    }
    if (i < N) {
        int p = bs[b] + s[t] - v;
        ptr[i] = p;
        if (i == N - 1) ptr[N] = p + v;
    }
}

// pre-fill srcs with dummy node N (pad slots gather the zero row)
__global__ void prefill_srcs_kernel(int* __restrict__ srcs, int n, int val) {
    int i = blockIdx.x * blockDim.x + threadIdx.x;
    if (i < n) srcs[i] = val;
}

// fill CSC buckets: srcs grouped by destination node (padded layout)
__global__ void fill_csc_kernel(const int* __restrict__ row,
                                const int* __restrict__ col,
                                const int* __restrict__ ptr,
                                int* __restrict__ cursor,
                                int* __restrict__ srcs, int E) {
    int e = blockIdx.x * blockDim.x + threadIdx.x;
    if (e < E) {
        int c = col[e];
        int pos = ptr[c] + atomicAdd(&cursor[c], 1);
        srcs[pos] = row[e];
    }
}

// v0 = dinv * x  (fp32 -> fp16 v-space), one thread per 4 dims
__global__ void scale_init_kernel(const float* __restrict__ x,
                                  const float* __restrict__ dinv,
                                  _Float16* __restrict__ v, int N) {
    int t = blockIdx.x * blockDim.x + threadIdx.x;
    if (t < N * (DIM / 4)) {
        int n = t >> 4;
        float d = dinv[n];
        float4 a = ((const float4*)x)[t];
        half4 h;
        h.x = (_Float16)(a.x * d);
        h.y = (_Float16)(a.y * d);
        h.z = (_Float16)(a.z * d);
        h.w = (_Float16)(a.w * d);
        ((half4*)v)[t] = h;
    }
}

// zero dummy row N of all 4 v-buffers (padded CSC edges point here)
__global__ void zero_dummy_kernel(_Float16* v1, _Float16* v3, _Float16* v7,
                                  _Float16* tA, int N) {
    int t = threadIdx.x;
    if (t < DIM) {
        size_t o = (size_t)N * DIM + t;
        v1[o] = (_Float16)0.f;
        v3[o] = (_Float16)0.f;
        v7[o] = (_Float16)0.f;
        tA[o] = (_Float16)0.f;
    }
}

// ---------------------------------------------------------------------------
// v-space propagate (all edge weights == 1), fp16 storage / fp32 accumulate:
//   vout[n][:] = dinv[n]^2 * ( v[n][:] + sum_{e->n} v[srcs[e]][:] )
// One wave per node; 8 lanes per source row (half8 = 16 B/lane); 8 edges per
// gather instruction. Buckets padded to x8 (dummy -> zero row) = no tails.
// Depth-2 software pipeline + unroll 4 keeps ~4 row-gathers in flight.
// Cross-group fold: shfl_xor 8/16/32. Lanes 0-7 write the row (128 B).
// ---------------------------------------------------------------------------
__launch_bounds__(256)
__global__ void spmv_v_kernel(const int* __restrict__ ptr,
                              const int* __restrict__ srcs,
                              const float* __restrict__ dinv,
                              const _Float16* __restrict__ v,
                              _Float16* __restrict__ vout, int N) {
    int wave = blockIdx.x * 4 + (threadIdx.x >> 6);
    int lane = threadIdx.x & 63;
    if (wave >= N) return;
    int beg = __builtin_amdgcn_readfirstlane(ptr[wave]);
    int end = __builtin_amdgcn_readfirstlane(ptr[wave + 1]);
    int grp = lane >> 3;          // edge slot 0..7
    int sub = lane & 7;           // 8-half chunk of the row

    float a0 = 0.f, a1 = 0.f, a2 = 0.f, a3 = 0.f;
    float a4 = 0.f, a5 = 0.f, a6 = 0.f, a7 = 0.f;

    if (beg < end) {
        int s_cur = srcs[beg + grp];
        half8 h_cur = *(const half8*)(v + (unsigned)s_cur * DIM + sub * 8);
        #pragma unroll 4
        for (int j = beg + 8; j < end; j += 8) {
            int s_nxt = srcs[j + grp];
            half8 h_nxt = *(const half8*)(v + (unsigned)s_nxt * DIM + sub * 8);
            a0 += (float)h_cur[0]; a1 += (float)h_cur[1];
            a2 += (float)h_cur[2]; a3 += (float)h_cur[3];
            a4 += (float)h_cur[4]; a5 += (float)h_cur[5];
            a6 += (float)h_cur[6]; a7 += (float)h_cur[7];
            h_cur = h_nxt;
        }
        a0 += (float)h_cur[0]; a1 += (float)h_cur[1];
        a2 += (float)h_cur[2]; a3 += (float)h_cur[3];
        a4 += (float)h_cur[4]; a5 += (float)h_cur[5];
        a6 += (float)h_cur[6]; a7 += (float)h_cur[7];
    }

    // fold the 8 edge groups (lane bits 3,4,5)
    a0 += __shfl_xor(a0, 8);  a1 += __shfl_xor(a1, 8);
    a2 += __shfl_xor(a2, 8);  a3 += __shfl_xor(a3, 8);
    a4 += __shfl_xor(a4, 8);  a5 += __shfl_xor(a5, 8);
    a6 += __shfl_xor(a6, 8);  a7 += __shfl_xor(a7, 8);
    a0 += __shfl_xor(a0, 16); a1 += __shfl_xor(a1, 16);
    a2 += __shfl_xor(a2, 16); a3 += __shfl_xor(a3, 16);
    a4 += __shfl_xor(a4, 16); a5 += __shfl_xor(a5, 16);
    a6 += __shfl_xor(a6, 16); a7 += __shfl_xor(a7, 16);
    a0 += __shfl_xor(a0, 32); a1 += __shfl_xor(a1, 32);
    a2 += __shfl_xor(a2, 32); a3 += __shfl_xor(a3, 32);
    a4 += __shfl_xor(a4, 32); a5 += __shfl_xor(a5, 32);
    a6 += __shfl_xor(a6, 32); a7 += __shfl_xor(a7, 32);

    if (grp == 0) {
        half8 hs = *(const half8*)(v + (unsigned)wave * DIM + sub * 8);
        float d = dinv[wave];
        float dd = d * d;
        half8 r;
        r[0] = (_Float16)(dd * (a0 + (float)hs[0]));
        r[1] = (_Float16)(dd * (a1 + (float)hs[1]));
        r[2] = (_Float16)(dd * (a2 + (float)hs[2]));
        r[3] = (_Float16)(dd * (a3 + (float)hs[3]));
        r[4] = (_Float16)(dd * (a4 + (float)hs[4]));
        r[5] = (_Float16)(dd * (a5 + (float)hs[5]));
        r[6] = (_Float16)(dd * (a6 + (float)hs[6]));
        r[7] = (_Float16)(dd * (a7 + (float)hs[7]));
        *(half8*)(vout + (unsigned)wave * DIM + sub * 8) = r;
    }
}

// ---------------------------------------------------------------------------
// Reference quirk: r never updates -> powers cumulative:
//   x_agg[1] = A x, x_agg[2] = A^3 x, x_agg[4] = A^7 x.
//   cat@W = x@W3 + p1@(W0-W3+W4) + p3@(W1-W4+W5) + p7@(W2-W5)
// weff layout: [src][k][d] flattened = [kk][d] with kk = src*64+k
// ---------------------------------------------------------------------------
__global__ void make_weff_kernel(const float* __restrict__ W,
                                 float* __restrict__ weff) {
    int t = blockIdx.x * blockDim.x + threadIdx.x;
    if (t < 64 * 64) {
        int k = t >> 6, d = t & 63;
        float w0 = W[(0 * 64 + k) * 64 + d];
        float w1 = W[(1 * 64 + k) * 64 + d];
        float w2 = W[(2 * 64 + k) * 64 + d];
        float w3 = W[(3 * 64 + k) * 64 + d];
        float w4 = W[(4 * 64 + k) * 64 + d];
        float w5 = W[(5 * 64 + k) * 64 + d];
        weff[(0 * 64 + k) * 64 + d] = w3;
        weff[(1 * 64 + k) * 64 + d] = w0 - w3 + w4;
        weff[(2 * 64 + k) * 64 + d] = w1 - w4 + w5;
        weff[(3 * 64 + k) * 64 + d] = w2 - w5;
    }
}

// ---------------------------------------------------------------------------
// MFMA combine (f16): out[16-node tile][64 dims] via mfma_f32_16x16x32_f16.
// Verified layouts (m89/m91, dtype-indep): A m=lane&15,k=quad*8+j;
// B n=lane&15,k=quad*8+j; D col=lane&15,row=quad*4+reg.
// ---------------------------------------------------------------------------
__launch_bounds__(256)
__global__ void combine_mfma_kernel(const float* __restrict__ x,
                                    const _Float16* __restrict__ v1,
                                    const _Float16* __restrict__ v3,
                                    const _Float16* __restrict__ v7,
                                    const float* __restrict__ rdinv,
                                    const float* __restrict__ weff,
                                    const float* __restrict__ bias,
                                    float* __restrict__ out, int N) {
    __shared__ _Float16 sWt[64][264];  // [dim][kk] transposed f16 W
    __shared__ _Float16 sA[16][264];   // [node][kk] f16 inputs

    int tid = threadIdx.x;
    for (int i = tid; i < 64 * 256; i += 256) {
        int kk = i >> 6, d = i & 63;
        sWt[d][kk] = (_Float16)weff[i];
    }
    int lane = tid & 63;
    int w = tid >> 6;
    int quad = lane >> 4;
    int col = lane & 15;
    int dim = w * 16 + col;
    float bv = bias[dim];

    int ngroups = (N + 15) / 16;
    for (int g = blockIdx.x; g < ngroups; g += gridDim.x) {
        int n0 = g * 16;
        __syncthreads();
        for (int i = tid; i < 1024; i += 256) {
            int node = i >> 6;
            int rem = i & 63;
            int src = rem >> 4;
            int f = rem & 15;
            int n = n0 + node;
            half4 hq = {(_Float16)0.f, (_Float16)0.f,
                        (_Float16)0.f, (_Float16)0.f};
            if (n < N) {
                if (src == 0) {
                    float4 val = *(const float4*)(x + (size_t)n * DIM + f * 4);
                    hq.x = (_Float16)val.x; hq.y = (_Float16)val.y;
                    hq.z = (_Float16)val.z; hq.w = (_Float16)val.w;
                } else {
                    const _Float16* p = (src == 1) ? v1 : (src == 2) ? v3 : v7;
                    half4 hv = *(const half4*)(p + (size_t)n * DIM + f * 4);
                    float rd = rdinv[n];
                    hq.x = (_Float16)((float)hv.x * rd);
                    hq.y = (_Float16)((float)hv.y * rd);
                    hq.z = (_Float16)((float)hv.z * rd);
                    hq.w = (_Float16)((float)hv.w * rd);
                }
            }
            *(half4*)&sA[node][src * 64 + f * 4] = hq;
        }
        __syncthreads();

        floatx4 acc = {0.f, 0.f, 0.f, 0.f};
        #pragma unroll
        for (int t = 0; t < 8; ++t) {
            int k0 = t * 32 + quad * 8;
            half8 af = *(const half8*)&sA[col][k0];
            half8 bf = *(const half8*)&sWt[dim][k0];
            acc = __builtin_amdgcn_mfma_f32_16x16x32_f16(af, bf, acc, 0, 0, 0);
        }
        #pragma unroll
        for (int r = 0; r < 4; ++r) {
            int n = n0 + quad * 4 + r;
            if (n < N) {
                float vv = acc[r] + bv;
                out[(size_t)n * DIM + dim] = fmaxf(vv, 0.f);
            }
        }
    }
}

extern "C" void kernel_launch(void* const* d_in, const int* in_sizes, int n_in,
                              void* d_out, int out_size, void* d_ws, size_t ws_size,
                              hipStream_t stream) {
    const float* x  = (const float*)d_in[0];
    const int*   ei = (const int*)d_in[1];
    const float* W  = (const float*)d_in[2];
    const float* b  = (const float*)d_in[3];
    float* out = (float*)d_out;

    const int N = in_sizes[0] / DIM;
    const int E = in_sizes[1] / 2;
    const int* row = ei;
    const int* col = ei + E;

    const size_t NDH = (size_t)(N + 1) * DIM;   // +1 dummy zero row
    const int Epad = E + 7 * N;                 // upper bound on padded edges
    float* ws = (float*)d_ws;
    float* dinv  = ws;                  // N floats
    float* rdinv = dinv + N;            // N floats
    float* weff  = rdinv + N;           // 4*64*64 = 16384 floats
    _Float16* v1 = (_Float16*)(weff + 4 * 64 * 64);  // NDH halves
    _Float16* v3 = v1 + NDH;            // NDH halves
    _Float16* v7 = v3 + NDH;            // NDH halves
    _Float16* tA = v7 + NDH;            // NDH halves
    int*   deg   = (int*)(tA + NDH);    // N
    int*   ptr   = deg + N;             // N+1
    int*   cur   = ptr + N + 1;         // N
    int*   bs    = cur + N;             // <=1024
    int*   srcs  = bs + 1024;           // Epad

    const int nb = (N + 255) / 256;

    // --- degree + dinv/rdinv ---
    hipMemsetAsync(deg, 0, (size_t)N * sizeof(int), stream);
    hipMemsetAsync(cur, 0, (size_t)N * sizeof(int), stream);
    count_deg_kernel<<<(E + 255) / 256, 256, 0, stream>>>(col, deg, E);
    dinv_kernel<<<nb, 256, 0, stream>>>(deg, dinv, rdinv, N);

    // --- exclusive scan of padded deg -> ptr ---
    reduce_chunks_kernel<<<nb, 256, 0, stream>>>(deg, bs, N);
    scan_block_sums_kernel<<<1, 1024, 0, stream>>>(bs, nb);
    scan_chunks_kernel<<<nb, 256, 0, stream>>>(deg, bs, ptr, N);

    // --- CSC fill (pad slots stay = N) ---
    prefill_srcs_kernel<<<(Epad + 255) / 256, 256, 0, stream>>>(srcs, Epad, N);
    fill_csc_kernel<<<(E + 255) / 256, 256, 0, stream>>>(row, col, ptr, cur,
                                                         srcs, E);

    // --- effective W ---
    make_weff_kernel<<<16, 256, 0, stream>>>(W, weff);

    const int initGrid = (N * (DIM / 4) + 255) / 256;
    const int propGrid = (N + 3) / 4;   // 4 nodes (waves) per 256-thread block
    auto prop = [&](const _Float16* src, _Float16* dst) {
        spmv_v_kernel<<<propGrid, 256, 0, stream>>>(ptr, srcs, dinv, src, dst, N);
    };

    // v0 = dinv * x (in tA); zero dummy rows
    scale_init_kernel<<<initGrid, 256, 0, stream>>>(x, dinv, tA, N);
    zero_dummy_kernel<<<1, 64, 0, stream>>>(v1, v3, v7, tA, N);

    prop(tA, v1);   // v1
    prop(v1, tA);   // v2
    prop(tA, v3);   // v3
    prop(v3, tA);   // v4
    prop(tA, v7);   // v5 (v7 as scratch)
    prop(v7, tA);   // v6
    prop(tA, v7);   // v7

    // --- combine (MFMA f16) ---
    combine_mfma_kernel<<<1024, 256, 0, stream>>>(x, v1, v3, v7, rdinv, weff,
                                                  b, out, N);
}

// Round 10
// 558.666 us; speedup vs baseline: 1.0991x; 1.0991x over previous
//
#include <hip/hip_runtime.h>

#define DIM 64
#define BIN_SHIFT 8          // 256 nodes per bin
#define BCAP 5120            // staging capacity per bin (mean 4092, +16 sigma)

typedef __attribute__((ext_vector_type(8))) _Float16 half8;
typedef __attribute__((ext_vector_type(4))) _Float16 half4;
typedef __attribute__((ext_vector_type(4))) float floatx4;

// ---------------------------------------------------------------------------
// deg[col[e]] += 1  (int atomics, one-time CSC build)
// ---------------------------------------------------------------------------
__global__ void count_deg_kernel(const int* __restrict__ col,
                                 int* __restrict__ deg, int E) {
    int e = blockIdx.x * blockDim.x + threadIdx.x;
    if (e < E) atomicAdd(&deg[col[e]], 1);
}

// dinv[i] = rsqrt(deg+1), rdinv[i] = sqrt(deg+1)
__global__ void dinv_kernel(const int* __restrict__ deg,
                            float* __restrict__ dinv,
                            float* __restrict__ rdinv, int N) {
    int i = blockIdx.x * blockDim.x + threadIdx.x;
    if (i < N) {
        float d = (float)deg[i] + 1.0f;
        dinv[i] = rsqrtf(d);
        rdinv[i] = sqrtf(d);
    }
}

// --------------------------- exclusive scan over PADDED degree -------------
// pdeg = (deg+3)&~3 so every CSC bucket is a multiple of 4 edges.
__global__ void reduce_chunks_kernel(const int* __restrict__ deg,
                                     int* __restrict__ bs, int N) {
    __shared__ int s[256];
    int t = threadIdx.x;
    int i = blockIdx.x * 256 + t;
    s[t] = (i < N) ? ((deg[i] + 3) & ~3) : 0;
    __syncthreads();
    for (int d = 128; d > 0; d >>= 1) {
        if (t < d) s[t] += s[t + d];
        __syncthreads();
    }
    if (t == 0) bs[blockIdx.x] = s[0];
}

__global__ void scan_block_sums_kernel(int* __restrict__ bs, int nb) {
    __shared__ int s[1024];
    int t = threadIdx.x;
    s[t] = (t < nb) ? bs[t] : 0;
    __syncthreads();
    for (int d = 1; d < 1024; d <<= 1) {
        int v = (t >= d) ? s[t - d] : 0;
        __syncthreads();
        s[t] += v;
        __syncthreads();
    }
    if (t < nb) bs[t] = (t == 0) ? 0 : s[t - 1];
}

__global__ void scan_chunks_kernel(const int* __restrict__ deg,
                                   const int* __restrict__ bs,
                                   int* __restrict__ ptr, int N) {
    __shared__ int s[256];
    int b = blockIdx.x, t = threadIdx.x;
    int i = b * 256 + t;
    int v = (i < N) ? ((deg[i] + 3) & ~3) : 0;
    s[t] = v;
    __syncthreads();
    for (int d = 1; d < 256; d <<= 1) {
        int u = (t >= d) ? s[t - d] : 0;
        __syncthreads();
        s[t] += u;
        __syncthreads();
    }
    if (i < N) {
        int p = bs[b] + s[t] - v;
        ptr[i] = p;
        if (i == N - 1) ptr[N] = p + v;
    }
}

// ---------------------------------------------------------------------------
// Pass A: bin edges by col>>8 into per-bin staging with chunk reservation.
// Each block: 4096 edges -> LDS histogram -> one global atomic per touched
// bin -> contiguous burst writes (~64 B runs) into staging[bin*BCAP ...].
// ---------------------------------------------------------------------------
__launch_bounds__(256)
__global__ void bin_edges_kernel(const int* __restrict__ row,
                                 const int* __restrict__ col,
                                 int* __restrict__ bin_cursor,
                                 int2* __restrict__ staging, int E) {
    __shared__ int hist[512];
    __shared__ int base[512];
    int tid = threadIdx.x;
    for (int i = tid; i < 512; i += 256) hist[i] = 0;
    __syncthreads();
    int e0 = blockIdx.x * 4096;
    int c[16];
    #pragma unroll
    for (int k = 0; k < 16; ++k) {
        int e = e0 + tid + k * 256;
        c[k] = (e < E) ? col[e] : -1;
        if (c[k] >= 0) atomicAdd(&hist[c[k] >> BIN_SHIFT], 1);
    }
    __syncthreads();
    for (int i = tid; i < 512; i += 256) {
        base[i] = (hist[i] > 0) ? atomicAdd(&bin_cursor[i], hist[i]) : 0;
        hist[i] = 0;   // reuse as intra-block offset
    }
    __syncthreads();
    #pragma unroll
    for (int k = 0; k < 16; ++k) {
        if (c[k] >= 0) {
            int e = e0 + tid + k * 256;
            int b = c[k] >> BIN_SHIFT;
            int idx = atomicAdd(&hist[b], 1);
            staging[(size_t)b * BCAP + base[b] + idx] = make_int2(row[e], c[k]);
        }
    }
}

// ---------------------------------------------------------------------------
// Pass B: one block per bin. LDS node-cursors; scatter srcs within the bin's
// ~18 KB contiguous region (L2-resident, full-line writeback). Fills pad
// slots (to x4) with dummy node in the same pass.
// ---------------------------------------------------------------------------
__launch_bounds__(256)
__global__ void fill_bins_kernel(const int2* __restrict__ staging,
                                 const int* __restrict__ bin_cursor,
                                 const int* __restrict__ ptr,
                                 int* __restrict__ srcs, int N, int dummy) {
    __shared__ int cur[256];
    int b = blockIdx.x;
    int tid = threadIdx.x;
    int n = (b << BIN_SHIFT) + tid;
    cur[tid] = (n < N) ? ptr[n] : 0;
    __syncthreads();
    int cnt = bin_cursor[b];
    for (int i = tid; i < cnt; i += 256) {
        int2 rc = staging[(size_t)b * BCAP + i];
        int pos = atomicAdd(&cur[rc.y & 255], 1);
        srcs[pos] = rc.x;
    }
    __syncthreads();
    if (n < N) {
        int e = cur[tid];            // == ptr[n] + deg[n]
        int stop = ptr[n + 1];
        for (; e < stop; ++e) srcs[e] = dummy;
    }
}

// v0 = dinv * x  (fp32 -> fp16 v-space), one thread per 4 dims
__global__ void scale_init_kernel(const float* __restrict__ x,
                                  const float* __restrict__ dinv,
                                  _Float16* __restrict__ v, int N) {
    int t = blockIdx.x * blockDim.x + threadIdx.x;
    if (t < N * (DIM / 4)) {
        int n = t >> 4;
        float d = dinv[n];
        float4 a = ((const float4*)x)[t];
        half4 h;
        h.x = (_Float16)(a.x * d);
        h.y = (_Float16)(a.y * d);
        h.z = (_Float16)(a.z * d);
        h.w = (_Float16)(a.w * d);
        ((half4*)v)[t] = h;
    }
}

// zero dummy row N of all 4 v-buffers (padded CSC edges point here)
__global__ void zero_dummy_kernel(_Float16* v1, _Float16* v3, _Float16* v7,
                                  _Float16* tA, int N) {
    int t = threadIdx.x;
    if (t < DIM) {
        size_t o = (size_t)N * DIM + t;
        v1[o] = (_Float16)0.f;
        v3[o] = (_Float16)0.f;
        v7[o] = (_Float16)0.f;
        tA[o] = (_Float16)0.f;
    }
}

// ---------------------------------------------------------------------------
// v-space propagate (all edge weights == 1), fp16 storage / fp32 accumulate:
//   vout[n][:] = dinv[n]^2 * ( v[n][:] + sum_{e->n} v[srcs[e]][:] )
// One wave per node; 16 lanes per source row (half4 = 8 B/lane); 4 edges per
// gather instruction. Buckets padded to x4 (dummy -> zero row) = no tails.
// Cross-group fold: shfl_xor 16/32. Lanes 0-15 write the row.
// ---------------------------------------------------------------------------
__launch_bounds__(256)
__global__ void spmv_v_kernel(const int* __restrict__ ptr,
                              const int* __restrict__ srcs,
                              const float* __restrict__ dinv,
                              const _Float16* __restrict__ v,
                              _Float16* __restrict__ vout, int N) {
    int wave = blockIdx.x * 4 + (threadIdx.x >> 6);
    int lane = threadIdx.x & 63;
    if (wave >= N) return;
    int beg = __builtin_amdgcn_readfirstlane(ptr[wave]);
    int end = __builtin_amdgcn_readfirstlane(ptr[wave + 1]);
    int grp = lane >> 4;          // edge slot 0..3
    int sub = lane & 15;          // dim quad
    float a0 = 0.f, a1 = 0.f, a2 = 0.f, a3 = 0.f;
    #pragma unroll 4
    for (int j = beg; j < end; j += 4) {
        int s = srcs[j + grp];
        half4 hv = *(const half4*)(v + (unsigned)s * DIM + sub * 4);
        a0 += (float)hv.x;
        a1 += (float)hv.y;
        a2 += (float)hv.z;
        a3 += (float)hv.w;
    }
    a0 += __shfl_xor(a0, 16); a1 += __shfl_xor(a1, 16);
    a2 += __shfl_xor(a2, 16); a3 += __shfl_xor(a3, 16);
    a0 += __shfl_xor(a0, 32); a1 += __shfl_xor(a1, 32);
    a2 += __shfl_xor(a2, 32); a3 += __shfl_xor(a3, 32);
    if (grp == 0) {
        half4 hs = *(const half4*)(v + (unsigned)wave * DIM + sub * 4);
        float d = dinv[wave];
        float dd = d * d;
        half4 r;
        r.x = (_Float16)(dd * (a0 + (float)hs.x));
        r.y = (_Float16)(dd * (a1 + (float)hs.y));
        r.z = (_Float16)(dd * (a2 + (float)hs.z));
        r.w = (_Float16)(dd * (a3 + (float)hs.w));
        *(half4*)(vout + (unsigned)wave * DIM + sub * 4) = r;
    }
}

// ---------------------------------------------------------------------------
// Reference quirk: r never updates -> powers cumulative:
//   x_agg[1] = A x, x_agg[2] = A^3 x, x_agg[4] = A^7 x.
//   cat@W = x@W3 + p1@(W0-W3+W4) + p3@(W1-W4+W5) + p7@(W2-W5)
// weff layout: [src][k][d] flattened = [kk][d] with kk = src*64+k
// ---------------------------------------------------------------------------
__global__ void make_weff_kernel(const float* __restrict__ W,
                                 float* __restrict__ weff) {
    int t = blockIdx.x * blockDim.x + threadIdx.x;
    if (t < 64 * 64) {
        int k = t >> 6, d = t & 63;
        float w0 = W[(0 * 64 + k) * 64 + d];
        float w1 = W[(1 * 64 + k) * 64 + d];
        float w2 = W[(2 * 64 + k) * 64 + d];
        float w3 = W[(3 * 64 + k) * 64 + d];
        float w4 = W[(4 * 64 + k) * 64 + d];
        float w5 = W[(5 * 64 + k) * 64 + d];
        weff[(0 * 64 + k) * 64 + d] = w3;
        weff[(1 * 64 + k) * 64 + d] = w0 - w3 + w4;
        weff[(2 * 64 + k) * 64 + d] = w1 - w4 + w5;
        weff[(3 * 64 + k) * 64 + d] = w2 - w5;
    }
}

// ---------------------------------------------------------------------------
// MFMA combine (f16): out[16-node tile][64 dims] via mfma_f32_16x16x32_f16.
// Verified layouts (m89/m91, dtype-indep): A m=lane&15,k=quad*8+j;
// B n=lane&15,k=quad*8+j; D col=lane&15,row=quad*4+reg.
// ---------------------------------------------------------------------------
__launch_bounds__(256)
__global__ void combine_mfma_kernel(const float* __restrict__ x,
                                    const _Float16* __restrict__ v1,
                                    const _Float16* __restrict__ v3,
                                    const _Float16* __restrict__ v7,
                                    const float* __restrict__ rdinv,
                                    const float* __restrict__ weff,
                                    const float* __restrict__ bias,
                                    float* __restrict__ out, int N) {
    __shared__ _Float16 sWt[64][264];  // [dim][kk] transposed f16 W
    __shared__ _Float16 sA[16][264];   // [node][kk] f16 inputs

    int tid = threadIdx.x;
    for (int i = tid; i < 64 * 256; i += 256) {
        int kk = i >> 6, d = i & 63;
        sWt[d][kk] = (_Float16)weff[i];
    }
    int lane = tid & 63;
    int w = tid >> 6;
    int quad = lane >> 4;
    int col = lane & 15;
    int dim = w * 16 + col;
    float bv = bias[dim];

    int ngroups = (N + 15) / 16;
    for (int g = blockIdx.x; g < ngroups; g += gridDim.x) {
        int n0 = g * 16;
        __syncthreads();
        for (int i = tid; i < 1024; i += 256) {
            int node = i >> 6;
            int rem = i & 63;
            int src = rem >> 4;
            int f = rem & 15;
            int n = n0 + node;
            half4 hq = {(_Float16)0.f, (_Float16)0.f,
                        (_Float16)0.f, (_Float16)0.f};
            if (n < N) {
                if (src == 0) {
                    float4 val = *(const float4*)(x + (size_t)n * DIM + f * 4);
                    hq.x = (_Float16)val.x; hq.y = (_Float16)val.y;
                    hq.z = (_Float16)val.z; hq.w = (_Float16)val.w;
                } else {
                    const _Float16* p = (src == 1) ? v1 : (src == 2) ? v3 : v7;
                    half4 hv = *(const half4*)(p + (size_t)n * DIM + f * 4);
                    float rd = rdinv[n];
                    hq.x = (_Float16)((float)hv.x * rd);
                    hq.y = (_Float16)((float)hv.y * rd);
                    hq.z = (_Float16)((float)hv.z * rd);
                    hq.w = (_Float16)((float)hv.w * rd);
                }
            }
            *(half4*)&sA[node][src * 64 + f * 4] = hq;
        }
        __syncthreads();

        floatx4 acc = {0.f, 0.f, 0.f, 0.f};
        #pragma unroll
        for (int t = 0; t < 8; ++t) {
            int k0 = t * 32 + quad * 8;
            half8 af = *(const half8*)&sA[col][k0];
            half8 bf = *(const half8*)&sWt[dim][k0];
            acc = __builtin_amdgcn_mfma_f32_16x16x32_f16(af, bf, acc, 0, 0, 0);
        }
        #pragma unroll
        for (int r = 0; r < 4; ++r) {
            int n = n0 + quad * 4 + r;
            if (n < N) {
                float vv = acc[r] + bv;
                out[(size_t)n * DIM + dim] = fmaxf(vv, 0.f);
            }
        }
    }
}

extern "C" void kernel_launch(void* const* d_in, const int* in_sizes, int n_in,
                              void* d_out, int out_size, void* d_ws, size_t ws_size,
                              hipStream_t stream) {
    const float* x  = (const float*)d_in[0];
    const int*   ei = (const int*)d_in[1];
    const float* W  = (const float*)d_in[2];
    const float* b  = (const float*)d_in[3];
    float* out = (float*)d_out;

    const int N = in_sizes[0] / DIM;
    const int E = in_sizes[1] / 2;
    const int* row = ei;
    const int* col = ei + E;

    const size_t NDH = (size_t)(N + 1) * DIM;   // +1 dummy zero row
    const int Epad = E + 3 * N;                 // upper bound on padded edges
    const int nbins = (N + 255) >> BIN_SHIFT;   // 256 nodes per bin

    // staging first (8-byte aligned at ws base)
    int2* staging = (int2*)d_ws;                        // 512*BCAP int2
    float* dinv  = (float*)(staging + (size_t)512 * BCAP);  // N
    float* rdinv = dinv + N;            // N
    float* weff  = rdinv + N;           // 16384
    _Float16* v1 = (_Float16*)(weff + 4 * 64 * 64);  // NDH halves
    _Float16* v3 = v1 + NDH;
    _Float16* v7 = v3 + NDH;
    _Float16* tA = v7 + NDH;
    int*   deg   = (int*)(tA + NDH);    // N
    int*   ptr   = deg + N;             // N+1
    int*   bs    = ptr + N + 1;         // <=1024
    int*   bin_cursor = bs + 1024;      // 512
    int*   srcs  = bin_cursor + 512;    // Epad

    const int nb = (N + 255) / 256;

    // --- degree + dinv/rdinv ---
    hipMemsetAsync(deg, 0, (size_t)N * sizeof(int), stream);
    hipMemsetAsync(bin_cursor, 0, 512 * sizeof(int), stream);
    count_deg_kernel<<<(E + 255) / 256, 256, 0, stream>>>(col, deg, E);
    dinv_kernel<<<nb, 256, 0, stream>>>(deg, dinv, rdinv, N);

    // --- exclusive scan of padded deg -> ptr ---
    reduce_chunks_kernel<<<nb, 256, 0, stream>>>(deg, bs, N);
    scan_block_sums_kernel<<<1, 1024, 0, stream>>>(bs, nb);
    scan_chunks_kernel<<<nb, 256, 0, stream>>>(deg, bs, ptr, N);

    // --- binned two-pass CSC build ---
    bin_edges_kernel<<<(E + 4095) / 4096, 256, 0, stream>>>(row, col,
                                                            bin_cursor,
                                                            staging, E);
    fill_bins_kernel<<<nbins, 256, 0, stream>>>(staging, bin_cursor, ptr,
                                                srcs, N, N);

    // --- effective W ---
    make_weff_kernel<<<16, 256, 0, stream>>>(W, weff);

    const int initGrid = (N * (DIM / 4) + 255) / 256;
    const int propGrid = (N + 3) / 4;   // 4 nodes (waves) per 256-thread block
    auto prop = [&](const _Float16* src, _Float16* dst) {
        spmv_v_kernel<<<propGrid, 256, 0, stream>>>(ptr, srcs, dinv, src, dst, N);
    };

    // v0 = dinv * x (in tA); zero dummy rows
    scale_init_kernel<<<initGrid, 256, 0, stream>>>(x, dinv, tA, N);
    zero_dummy_kernel<<<1, 64, 0, stream>>>(v1, v3, v7, tA, N);

    prop(tA, v1);   // v1
    prop(v1, tA);   // v2
    prop(tA, v3);   // v3
    prop(v3, tA);   // v4
    prop(tA, v7);   // v5 (v7 as scratch)
    prop(v7, tA);   // v6
    prop(tA, v7);   // v7

    // --- combine (MFMA f16) ---
    combine_mfma_kernel<<<1024, 256, 0, stream>>>(x, v1, v3, v7, rdinv, weff,
                                                  b, out, N);
}

// Round 11
// 491.860 us; speedup vs baseline: 1.2484x; 1.1358x over previous
//
#include <hip/hip_runtime.h>

#define DIM 64
#define BIN_SHIFT 8          // 256 nodes per bin
#define BCAP 5120            // staging capacity per bin (mean 4092, +16 sigma)

typedef __attribute__((ext_vector_type(8))) _Float16 half8;
typedef __attribute__((ext_vector_type(4))) _Float16 half4;
typedef __attribute__((ext_vector_type(4))) float floatx4;

// ---------------------------------------------------------------------------
// Pass A: bin edges by col>>8 into per-bin staging with chunk reservation.
// Each block: 4096 edges -> LDS histogram -> one global atomic per touched
// bin -> contiguous burst writes into staging[bin*BCAP ...].
// ---------------------------------------------------------------------------
__launch_bounds__(256)
__global__ void bin_edges_kernel(const int* __restrict__ row,
                                 const int* __restrict__ col,
                                 int* __restrict__ bin_cursor,
                                 int2* __restrict__ staging, int E) {
    __shared__ int hist[512];
    __shared__ int base[512];
    int tid = threadIdx.x;
    for (int i = tid; i < 512; i += 256) hist[i] = 0;
    __syncthreads();
    int e0 = blockIdx.x * 4096;
    int c[16];
    #pragma unroll
    for (int k = 0; k < 16; ++k) {
        int e = e0 + tid + k * 256;
        c[k] = (e < E) ? col[e] : -1;
        if (c[k] >= 0) atomicAdd(&hist[c[k] >> BIN_SHIFT], 1);
    }
    __syncthreads();
    for (int i = tid; i < 512; i += 256) {
        base[i] = (hist[i] > 0) ? atomicAdd(&bin_cursor[i], hist[i]) : 0;
        hist[i] = 0;   // reuse as intra-block offset
    }
    __syncthreads();
    #pragma unroll
    for (int k = 0; k < 16; ++k) {
        if (c[k] >= 0) {
            int e = e0 + tid + k * 256;
            int b = c[k] >> BIN_SHIFT;
            int idx = atomicAdd(&hist[b], 1);
            staging[(size_t)b * BCAP + base[b] + idx] = make_int2(row[e], c[k]);
        }
    }
}

// ---------------------------------------------------------------------------
// Per-bin degree count: one block per bin; LDS histogram over the bin's
// staging slice (contiguous ~33 KB read); contiguous writes of deg/dinv/rdinv.
// Replaces 1.6M random global atomics (70 us, 50 MB WRITE) with LDS atomics.
// ---------------------------------------------------------------------------
__launch_bounds__(256)
__global__ void count_deg_bins_kernel(const int2* __restrict__ staging,
                                      const int* __restrict__ bin_cursor,
                                      int* __restrict__ deg,
                                      float* __restrict__ dinv,
                                      float* __restrict__ rdinv, int N) {
    __shared__ int hist[256];
    int b = blockIdx.x;
    int tid = threadIdx.x;
    hist[tid] = 0;
    __syncthreads();
    int cnt = bin_cursor[b];
    for (int i = tid; i < cnt; i += 256)
        atomicAdd(&hist[staging[(size_t)b * BCAP + i].y & 255], 1);
    __syncthreads();
    int n = (b << BIN_SHIFT) + tid;
    if (n < N) {
        int dg = hist[tid];
        deg[n] = dg;
        float d = (float)dg + 1.0f;
        dinv[n] = rsqrtf(d);
        rdinv[n] = sqrtf(d);
    }
}

// --------------------------- exclusive scan over PADDED degree -------------
// pdeg = (deg+3)&~3 so every CSC bucket is a multiple of 4 edges.
__global__ void reduce_chunks_kernel(const int* __restrict__ deg,
                                     int* __restrict__ bs, int N) {
    __shared__ int s[256];
    int t = threadIdx.x;
    int i = blockIdx.x * 256 + t;
    s[t] = (i < N) ? ((deg[i] + 3) & ~3) : 0;
    __syncthreads();
    for (int d = 128; d > 0; d >>= 1) {
        if (t < d) s[t] += s[t + d];
        __syncthreads();
    }
    if (t == 0) bs[blockIdx.x] = s[0];
}

__global__ void scan_block_sums_kernel(int* __restrict__ bs, int nb) {
    __shared__ int s[1024];
    int t = threadIdx.x;
    s[t] = (t < nb) ? bs[t] : 0;
    __syncthreads();
    for (int d = 1; d < 1024; d <<= 1) {
        int v = (t >= d) ? s[t - d] : 0;
        __syncthreads();
        s[t] += v;
        __syncthreads();
    }
    if (t < nb) bs[t] = (t == 0) ? 0 : s[t - 1];
}

__global__ void scan_chunks_kernel(const int* __restrict__ deg,
                                   const int* __restrict__ bs,
                                   int* __restrict__ ptr, int N) {
    __shared__ int s[256];
    int b = blockIdx.x, t = threadIdx.x;
    int i = b * 256 + t;
    int v = (i < N) ? ((deg[i] + 3) & ~3) : 0;
    s[t] = v;
    __syncthreads();
    for (int d = 1; d < 256; d <<= 1) {
        int u = (t >= d) ? s[t - d] : 0;
        __syncthreads();
        s[t] += u;
        __syncthreads();
    }
    if (i < N) {
        int p = bs[b] + s[t] - v;
        ptr[i] = p;
        if (i == N - 1) ptr[N] = p + v;
    }
}

// ---------------------------------------------------------------------------
// Pass B: one block per bin. LDS node-cursors; scatter srcs within the bin's
// ~18 KB contiguous region (L2-resident, full-line writeback). Fills pad
// slots (to x4) with dummy node in the same pass.
// ---------------------------------------------------------------------------
__launch_bounds__(256)
__global__ void fill_bins_kernel(const int2* __restrict__ staging,
                                 const int* __restrict__ bin_cursor,
                                 const int* __restrict__ ptr,
                                 int* __restrict__ srcs, int N, int dummy) {
    __shared__ int cur[256];
    int b = blockIdx.x;
    int tid = threadIdx.x;
    int n = (b << BIN_SHIFT) + tid;
    cur[tid] = (n < N) ? ptr[n] : 0;
    __syncthreads();
    int cnt = bin_cursor[b];
    for (int i = tid; i < cnt; i += 256) {
        int2 rc = staging[(size_t)b * BCAP + i];
        int pos = atomicAdd(&cur[rc.y & 255], 1);
        srcs[pos] = rc.x;
    }
    __syncthreads();
    if (n < N) {
        int e = cur[tid];            // == ptr[n] + deg[n]
        int stop = ptr[n + 1];
        for (; e < stop; ++e) srcs[e] = dummy;
    }
}

// v0 = dinv * x  (fp32 -> fp16 v-space), one thread per 4 dims
__global__ void scale_init_kernel(const float* __restrict__ x,
                                  const float* __restrict__ dinv,
                                  _Float16* __restrict__ v, int N) {
    int t = blockIdx.x * blockDim.x + threadIdx.x;
    if (t < N * (DIM / 4)) {
        int n = t >> 4;
        float d = dinv[n];
        float4 a = ((const float4*)x)[t];
        half4 h;
        h.x = (_Float16)(a.x * d);
        h.y = (_Float16)(a.y * d);
        h.z = (_Float16)(a.z * d);
        h.w = (_Float16)(a.w * d);
        ((half4*)v)[t] = h;
    }
}

// zero dummy row N of all 4 v-buffers (padded CSC edges point here)
__global__ void zero_dummy_kernel(_Float16* v1, _Float16* v3, _Float16* v7,
                                  _Float16* tA, int N) {
    int t = threadIdx.x;
    if (t < DIM) {
        size_t o = (size_t)N * DIM + t;
        v1[o] = (_Float16)0.f;
        v3[o] = (_Float16)0.f;
        v7[o] = (_Float16)0.f;
        tA[o] = (_Float16)0.f;
    }
}

// ---------------------------------------------------------------------------
// v-space propagate (all edge weights == 1), fp16 storage / fp32 accumulate:
//   vout[n][:] = dinv[n]^2 * ( v[n][:] + sum_{e->n} v[srcs[e]][:] )
// One wave per node; 16 lanes per source row (half4 = 8 B/lane); 4 edges per
// gather instruction. Buckets padded to x4 (dummy -> zero row) = no tails.
// Cross-group fold: shfl_xor 16/32. Lanes 0-15 write the row.
// ---------------------------------------------------------------------------
__launch_bounds__(256)
__global__ void spmv_v_kernel(const int* __restrict__ ptr,
                              const int* __restrict__ srcs,
                              const float* __restrict__ dinv,
                              const _Float16* __restrict__ v,
                              _Float16* __restrict__ vout, int N) {
    int wave = blockIdx.x * 4 + (threadIdx.x >> 6);
    int lane = threadIdx.x & 63;
    if (wave >= N) return;
    int beg = __builtin_amdgcn_readfirstlane(ptr[wave]);
    int end = __builtin_amdgcn_readfirstlane(ptr[wave + 1]);
    int grp = lane >> 4;          // edge slot 0..3
    int sub = lane & 15;          // dim quad
    float a0 = 0.f, a1 = 0.f, a2 = 0.f, a3 = 0.f;
    #pragma unroll 4
    for (int j = beg; j < end; j += 4) {
        int s = srcs[j + grp];
        half4 hv = *(const half4*)(v + (unsigned)s * DIM + sub * 4);
        a0 += (float)hv.x;
        a1 += (float)hv.y;
        a2 += (float)hv.z;
        a3 += (float)hv.w;
    }
    a0 += __shfl_xor(a0, 16); a1 += __shfl_xor(a1, 16);
    a2 += __shfl_xor(a2, 16); a3 += __shfl_xor(a3, 16);
    a0 += __shfl_xor(a0, 32); a1 += __shfl_xor(a1, 32);
    a2 += __shfl_xor(a2, 32); a3 += __shfl_xor(a3, 32);
    if (grp == 0) {
        half4 hs = *(const half4*)(v + (unsigned)wave * DIM + sub * 4);
        float d = dinv[wave];
        float dd = d * d;
        half4 r;
        r.x = (_Float16)(dd * (a0 + (float)hs.x));
        r.y = (_Float16)(dd * (a1 + (float)hs.y));
        r.z = (_Float16)(dd * (a2 + (float)hs.z));
        r.w = (_Float16)(dd * (a3 + (float)hs.w));
        *(half4*)(vout + (unsigned)wave * DIM + sub * 4) = r;
    }
}

// ---------------------------------------------------------------------------
// Reference quirk: r never updates -> powers cumulative:
//   x_agg[1] = A x, x_agg[2] = A^3 x, x_agg[4] = A^7 x.
//   cat@W = x@W3 + p1@(W0-W3+W4) + p3@(W1-W4+W5) + p7@(W2-W5)
// weff layout: [src][k][d] flattened = [kk][d] with kk = src*64+k
// ---------------------------------------------------------------------------
__global__ void make_weff_kernel(const float* __restrict__ W,
                                 float* __restrict__ weff) {
    int t = blockIdx.x * blockDim.x + threadIdx.x;
    if (t < 64 * 64) {
        int k = t >> 6, d = t & 63;
        float w0 = W[(0 * 64 + k) * 64 + d];
        float w1 = W[(1 * 64 + k) * 64 + d];
        float w2 = W[(2 * 64 + k) * 64 + d];
        float w3 = W[(3 * 64 + k) * 64 + d];
        float w4 = W[(4 * 64 + k) * 64 + d];
        float w5 = W[(5 * 64 + k) * 64 + d];
        weff[(0 * 64 + k) * 64 + d] = w3;
        weff[(1 * 64 + k) * 64 + d] = w0 - w3 + w4;
        weff[(2 * 64 + k) * 64 + d] = w1 - w4 + w5;
        weff[(3 * 64 + k) * 64 + d] = w2 - w5;
    }
}

// ---------------------------------------------------------------------------
// MFMA combine (f16): out[16-node tile][64 dims] via mfma_f32_16x16x32_f16.
// Verified layouts (m89/m91, dtype-indep): A m=lane&15,k=quad*8+j;
// B n=lane&15,k=quad*8+j; D col=lane&15,row=quad*4+reg.
// ---------------------------------------------------------------------------
__launch_bounds__(256)
__global__ void combine_mfma_kernel(const float* __restrict__ x,
                                    const _Float16* __restrict__ v1,
                                    const _Float16* __restrict__ v3,
                                    const _Float16* __restrict__ v7,
                                    const float* __restrict__ rdinv,
                                    const float* __restrict__ weff,
                                    const float* __restrict__ bias,
                                    float* __restrict__ out, int N) {
    __shared__ _Float16 sWt[64][264];  // [dim][kk] transposed f16 W
    __shared__ _Float16 sA[16][264];   // [node][kk] f16 inputs

    int tid = threadIdx.x;
    for (int i = tid; i < 64 * 256; i += 256) {
        int kk = i >> 6, d = i & 63;
        sWt[d][kk] = (_Float16)weff[i];
    }
    int lane = tid & 63;
    int w = tid >> 6;
    int quad = lane >> 4;
    int col = lane & 15;
    int dim = w * 16 + col;
    float bv = bias[dim];

    int ngroups = (N + 15) / 16;
    for (int g = blockIdx.x; g < ngroups; g += gridDim.x) {
        int n0 = g * 16;
        __syncthreads();
        for (int i = tid; i < 1024; i += 256) {
            int node = i >> 6;
            int rem = i & 63;
            int src = rem >> 4;
            int f = rem & 15;
            int n = n0 + node;
            half4 hq = {(_Float16)0.f, (_Float16)0.f,
                        (_Float16)0.f, (_Float16)0.f};
            if (n < N) {
                if (src == 0) {
                    float4 val = *(const float4*)(x + (size_t)n * DIM + f * 4);
                    hq.x = (_Float16)val.x; hq.y = (_Float16)val.y;
                    hq.z = (_Float16)val.z; hq.w = (_Float16)val.w;
                } else {
                    const _Float16* p = (src == 1) ? v1 : (src == 2) ? v3 : v7;
                    half4 hv = *(const half4*)(p + (size_t)n * DIM + f * 4);
                    float rd = rdinv[n];
                    hq.x = (_Float16)((float)hv.x * rd);
                    hq.y = (_Float16)((float)hv.y * rd);
                    hq.z = (_Float16)((float)hv.z * rd);
                    hq.w = (_Float16)((float)hv.w * rd);
                }
            }
            *(half4*)&sA[node][src * 64 + f * 4] = hq;
        }
        __syncthreads();

        floatx4 acc = {0.f, 0.f, 0.f, 0.f};
        #pragma unroll
        for (int t = 0; t < 8; ++t) {
            int k0 = t * 32 + quad * 8;
            half8 af = *(const half8*)&sA[col][k0];
            half8 bf = *(const half8*)&sWt[dim][k0];
            acc = __builtin_amdgcn_mfma_f32_16x16x32_f16(af, bf, acc, 0, 0, 0);
        }
        #pragma unroll
        for (int r = 0; r < 4; ++r) {
            int n = n0 + quad * 4 + r;
            if (n < N) {
                float vv = acc[r] + bv;
                out[(size_t)n * DIM + dim] = fmaxf(vv, 0.f);
            }
        }
    }
}

extern "C" void kernel_launch(void* const* d_in, const int* in_sizes, int n_in,
                              void* d_out, int out_size, void* d_ws, size_t ws_size,
                              hipStream_t stream) {
    const float* x  = (const float*)d_in[0];
    const int*   ei = (const int*)d_in[1];
    const float* W  = (const float*)d_in[2];
    const float* b  = (const float*)d_in[3];
    float* out = (float*)d_out;

    const int N = in_sizes[0] / DIM;
    const int E = in_sizes[1] / 2;
    const int* row = ei;
    const int* col = ei + E;

    const size_t NDH = (size_t)(N + 1) * DIM;   // +1 dummy zero row
    const int nbins = (N + 255) >> BIN_SHIFT;   // 256 nodes per bin

    // staging first (8-byte aligned at ws base)
    int2* staging = (int2*)d_ws;                        // 512*BCAP int2
    float* dinv  = (float*)(staging + (size_t)512 * BCAP);  // N
    float* rdinv = dinv + N;            // N
    float* weff  = rdinv + N;           // 16384
    _Float16* v1 = (_Float16*)(weff + 4 * 64 * 64);  // NDH halves
    _Float16* v3 = v1 + NDH;
    _Float16* v7 = v3 + NDH;
    _Float16* tA = v7 + NDH;
    int*   deg   = (int*)(tA + NDH);    // N
    int*   ptr   = deg + N;             // N+1
    int*   bs    = ptr + N + 1;         // <=1024
    int*   bin_cursor = bs + 1024;      // 512
    int*   srcs  = bin_cursor + 512;    // E + 3N

    const int nb = (N + 255) / 256;

    // --- bin edges (needs only bin_cursor zeroed) ---
    hipMemsetAsync(bin_cursor, 0, 512 * sizeof(int), stream);
    bin_edges_kernel<<<(E + 4095) / 4096, 256, 0, stream>>>(row, col,
                                                            bin_cursor,
                                                            staging, E);

    // --- per-bin degree + dinv/rdinv (contiguous writes, no global atomics) ---
    count_deg_bins_kernel<<<nbins, 256, 0, stream>>>(staging, bin_cursor,
                                                     deg, dinv, rdinv, N);

    // --- exclusive scan of padded deg -> ptr ---
    reduce_chunks_kernel<<<nb, 256, 0, stream>>>(deg, bs, N);
    scan_block_sums_kernel<<<1, 1024, 0, stream>>>(bs, nb);
    scan_chunks_kernel<<<nb, 256, 0, stream>>>(deg, bs, ptr, N);

    // --- CSC fill from bins ---
    fill_bins_kernel<<<nbins, 256, 0, stream>>>(staging, bin_cursor, ptr,
                                                srcs, N, N);

    // --- effective W ---
    make_weff_kernel<<<16, 256, 0, stream>>>(W, weff);

    const int initGrid = (N * (DIM / 4) + 255) / 256;
    const int propGrid = (N + 3) / 4;   // 4 nodes (waves) per 256-thread block
    auto prop = [&](const _Float16* src, _Float16* dst) {
        spmv_v_kernel<<<propGrid, 256, 0, stream>>>(ptr, srcs, dinv, src, dst, N);
    };

    // v0 = dinv * x (in tA); zero dummy rows
    scale_init_kernel<<<initGrid, 256, 0, stream>>>(x, dinv, tA, N);
    zero_dummy_kernel<<<1, 64, 0, stream>>>(v1, v3, v7, tA, N);

    prop(tA, v1);   // v1
    prop(v1, tA);   // v2
    prop(tA, v3);   // v3
    prop(v3, tA);   // v4
    prop(tA, v7);   // v5 (v7 as scratch)
    prop(v7, tA);   // v6
    prop(tA, v7);   // v7

    // --- combine (MFMA f16) ---
    combine_mfma_kernel<<<1024, 256, 0, stream>>>(x, v1, v3, v7, rdinv, weff,
                                                  b, out, N);
}